// Round 5
// baseline (218.061 us; speedup 1.0000x reference)
//
#include <hip/hip_runtime.h>

// Forbid FMA contraction: the reference evaluates each f32 op separately; a
// fused (A+B) - ih*iw would change rounding and can flip labels at 0.3/0.7.
#pragma clang fp contract(off)

#define N_ANCH   262144
#define N_GT     256
#define MAX_POSK 128
#define TOTALK   256
#define NBINS    2048
#define CAP      2048
#define BORDCAP  2048

// ---------------------------------------------------------------------------
// Threefry-2x32 (exact JAX PRNG). 20 rounds — VERIFIED bit-exact (R2-R4).
// ---------------------------------------------------------------------------
struct TF2 { unsigned a, b; };

__host__ __device__ constexpr unsigned rotl32(unsigned v, int d) {
  return (v << d) | (v >> (32 - d));
}

__host__ __device__ constexpr TF2 tf2x32(unsigned k0, unsigned k1,
                                         unsigned x0, unsigned x1) {
  unsigned ks2 = k0 ^ k1 ^ 0x1BD11BDAu;
  x0 += k0; x1 += k1;
  x0 += x1; x1 = rotl32(x1, 13); x1 ^= x0;
  x0 += x1; x1 = rotl32(x1, 15); x1 ^= x0;
  x0 += x1; x1 = rotl32(x1, 26); x1 ^= x0;
  x0 += x1; x1 = rotl32(x1,  6); x1 ^= x0;
  x0 += k1; x1 += ks2 + 1u;
  x0 += x1; x1 = rotl32(x1, 17); x1 ^= x0;
  x0 += x1; x1 = rotl32(x1, 29); x1 ^= x0;
  x0 += x1; x1 = rotl32(x1, 16); x1 ^= x0;
  x0 += x1; x1 = rotl32(x1, 24); x1 ^= x0;
  x0 += ks2; x1 += k0 + 2u;
  x0 += x1; x1 = rotl32(x1, 13); x1 ^= x0;
  x0 += x1; x1 = rotl32(x1, 15); x1 ^= x0;
  x0 += x1; x1 = rotl32(x1, 26); x1 ^= x0;
  x0 += x1; x1 = rotl32(x1,  6); x1 ^= x0;
  x0 += k0; x1 += k1 + 3u;
  x0 += x1; x1 = rotl32(x1, 17); x1 ^= x0;
  x0 += x1; x1 = rotl32(x1, 29); x1 ^= x0;
  x0 += x1; x1 = rotl32(x1, 16); x1 ^= x0;
  x0 += x1; x1 = rotl32(x1, 24); x1 ^= x0;
  x0 += k1; x1 += ks2 + 4u;
  x0 += x1; x1 = rotl32(x1, 13); x1 ^= x0;
  x0 += x1; x1 = rotl32(x1, 15); x1 ^= x0;
  x0 += x1; x1 = rotl32(x1, 26); x1 ^= x0;
  x0 += x1; x1 = rotl32(x1,  6); x1 ^= x0;
  x0 += ks2; x1 += k0 + 5u;
  return TF2{x0, x1};
}

// jax.random.key(42); partitionable threefry (verified):
//   split: child i = both words of E(key,(0,i));  bits[i] = E(key,(0,i)).a ^ .b
constexpr unsigned KP0 = tf2x32(0u, 42u, 0u, 0u).a;
constexpr unsigned KP1 = tf2x32(0u, 42u, 0u, 0u).b;
constexpr unsigned KN0 = tf2x32(0u, 42u, 0u, 1u).a;
constexpr unsigned KN1 = tf2x32(0u, 42u, 0u, 1u).b;

__device__ inline unsigned score_bits(unsigned k0, unsigned k1, unsigned i) {
  TF2 r = tf2x32(k0, k1, 0u, i);
  return r.a ^ r.b;
}

// Exact threshold constants (verified R3/R4):
// round32(q) > 0.7f  <=> q >= MPOSD ;  round32(q) >= 0.3f <=> q >= MNEGD
constexpr double MPOSD = (double)0.7f + 0x1p-25;
constexpr double MNEGD = (double)0.3f - 0x1p-26;
// inter >= m*(A+B-inter) <=> inter >= [m/(1+m)]*(A+B)
constexpr float CPF = (float)(MPOSD / (1.0 + MPOSD));
constexpr float CNF = (float)(MNEGD / (1.0 + MNEGD));

// ---------------------------------------------------------------------------
// Device-global scratch. g_hist/g_nbord are zero at entry to k_main on EVERY
// call: zero-initialized at module load, and re-zeroed by k_tail's cleanup
// phase at the end of every launch (harness only poisons d_out/d_ws).
// ---------------------------------------------------------------------------
__device__ unsigned g_packed[N_ANCH];  // (sbits & ~511) | (label+1)
__device__ int      g_hist[2][NBINS];
__device__ int      g_nbord;
__device__ int      g_bord[BORDCAP];

// ---------------------------------------------------------------------------
__device__ inline void finish_anchor(int i, float4 a, float mp, float mn,
                                     float Hf, float Wf) {
  const float A = (a.z - a.x) * (a.w - a.y);
  const float mrp = mp - CPF * A;     // sign == sign of best q vs MPOSD (+/- band)
  const float mrn = mn - CNF * A;
  const bool inside = (a.x >= 0.0f) && (a.y >= 0.0f) && (a.z <= Hf) && (a.w <= Wf);
  // rounding-error bound ~6*2^-24*(A+B); band = 12*2^-24*(A+65536) >= 2x slack
  const float band = 0x1.8p-21f * (A + 65536.0f);
  const bool pos = mrp > band;
  const bool nny = mrn > band;
  int lab = pos ? 1 : (nny ? -1 : 0);
  if (!inside) lab = -1;

  unsigned sb = 0u;
  if (lab >= 0) {
    sb = score_bits(lab == 1 ? KP0 : KN0, lab == 1 ? KP1 : KN1, (unsigned)i);
    atomicAdd(&g_hist[lab == 1 ? 0 : 1][sb >> 21], 1);
  }
  g_packed[i] = (sb & ~511u) | (unsigned)(lab + 1);

  if (inside && (fabsf(mrp) <= band || fabsf(mrn) <= band)) {
    int b = atomicAdd(&g_nbord, 1);
    if (b < BORDCAP) g_bord[b] = i;
  }
}

// 2 anchors/thread: 256 division-free IoU threshold tests each, score + hist.
// (Byte-identical math to the R4-verified version.)
__global__ __launch_bounds__(256) void k_main(const float4* __restrict__ anchors,
                                              const float4* __restrict__ gt,
                                              const int* __restrict__ ph,
                                              const int* __restrict__ pw) {
  __shared__ float4 s_gt[N_GT];
  __shared__ float  s_tp[N_GT];   // CPF * B_j
  __shared__ float  s_tn[N_GT];   // CNF * B_j
  const int tid = threadIdx.x;
  {
    float4 g = gt[tid];
    s_gt[tid] = g;
    float B = (g.z - g.x) * (g.w - g.y);
    s_tp[tid] = CPF * B;
    s_tn[tid] = CNF * B;
  }
  __syncthreads();

  const int i0 = blockIdx.x * 512 + tid;
  const int i1 = i0 + 256;
  const float4 a0 = anchors[i0];
  const float4 a1 = anchors[i1];
  const float Hf = (float)(*ph);
  const float Wf = (float)(*pw);

  float mp0 = -1e30f, mn0 = -1e30f, mp1 = -1e30f, mn1 = -1e30f;
  #pragma unroll 4
  for (int j = 0; j < N_GT; ++j) {
    const float4 b = s_gt[j];
    const float tp = s_tp[j];
    const float tn = s_tn[j];
    float ih0 = fmaxf(fminf(a0.z, b.z) - fmaxf(a0.x, b.x), 0.0f);
    float iw0 = fmaxf(fminf(a0.w, b.w) - fmaxf(a0.y, b.y), 0.0f);
    float in0 = ih0 * iw0;
    mp0 = fmaxf(mp0, in0 - tp);
    mn0 = fmaxf(mn0, in0 - tn);
    float ih1 = fmaxf(fminf(a1.z, b.z) - fmaxf(a1.x, b.x), 0.0f);
    float iw1 = fmaxf(fminf(a1.w, b.w) - fmaxf(a1.y, b.y), 0.0f);
    float in1 = ih1 * iw1;
    mp1 = fmaxf(mp1, in1 - tp);
    mn1 = fmaxf(mn1, in1 - tn);
  }
  finish_anchor(i0, a0, mp0, mn0, Hf, Wf);
  finish_anchor(i1, a1, mp1, mn1, Hf, Wf);
}

__device__ int find_cut(const int* cs, const int* hist, int K) {
  if (K <= 0) return NBINS;
  int suffix = 0, c = 127;
  for (; c >= 0; --c) {
    if (suffix + cs[c] >= K) break;
    suffix += cs[c];
  }
  if (c < 0) return 0;
  for (int b = c * 16 + 15; b >= c * 16; --b) {
    suffix += hist[b];
    if (suffix >= K) return b;
  }
  return c * 16;
}

__device__ inline unsigned long long shfl_xor_u64(unsigned long long v, int m) {
  unsigned lo = (unsigned)v, hi = (unsigned)(v >> 32);
  lo = __shfl_xor(lo, m, 64);
  hi = __shfl_xor(hi, m, 64);
  return ((unsigned long long)hi << 32) | lo;
}

// Fused tail: border-resolve -> totals/cuts -> compact -> rank-write ->
// argmax -> cleanup-for-next-call.  One block, 1024 threads.
__global__ __launch_bounds__(1024) void k_tail(const float4* __restrict__ anchors,
                                               const float4* __restrict__ gt,
                                               int* __restrict__ out) {
  __shared__ unsigned long long s_keys[2][CAP];   // (score23<<32)|~idx
  __shared__ int s_csp[128], s_csn[128];
  __shared__ int s_sel[TOTALK];                    // selected anchor idx per slot
  __shared__ int s_cut[2], s_cnt[2], s_cur[2];
  const int tid  = threadIdx.x;
  const int wid  = tid >> 6, lane = tid & 63;

  // ---- Phase A: border resolve (one anchor per wave, exact f64 compares) ----
  int nb = g_nbord; if (nb > BORDCAP) nb = BORDCAP;
  for (int b = wid; b < nb; b += 16) {
    const int i = g_bord[b];
    const float4 a = anchors[i];
    const float A = (a.z - a.x) * (a.w - a.y);
    bool p = false, nn = false;
    #pragma unroll
    for (int k = 0; k < 4; ++k) {
      const int j = lane + 64 * k;
      float4 bb = gt[j];
      float ih = fmaxf(fminf(a.z, bb.z) - fmaxf(a.x, bb.x), 0.0f);
      float iw = fmaxf(fminf(a.w, bb.w) - fmaxf(a.y, bb.y), 0.0f);
      float inter = ih * iw;
      float Bar = (bb.z - bb.x) * (bb.w - bb.y);
      float uni = (A + Bar) - inter;          // exact reference f32 rounding
      double id = (double)inter, ud = (double)uni;
      p  |= (id >= MPOSD * ud);               // exact: 25x24-bit products in f64
      nn |= (id >= MNEGD * ud);
    }
    unsigned long long bp = __ballot(p);
    unsigned long long bn = __ballot(nn);
    if (lane == 0) {
      int newlab = bp ? 1 : (bn ? -1 : 0);
      unsigned old = g_packed[i];
      int oldlab = (int)(old & 3u) - 1;
      if (newlab != oldlab) {
        if (oldlab >= 0) atomicAdd(&g_hist[oldlab == 1 ? 0 : 1][old >> 21], -1);
        unsigned sb = 0u;
        if (newlab >= 0) {
          sb = score_bits(newlab == 1 ? KP0 : KN0, newlab == 1 ? KP1 : KN1, (unsigned)i);
          atomicAdd(&g_hist[newlab == 1 ? 0 : 1][sb >> 21], 1);
        }
        g_packed[i] = (sb & ~511u) | (unsigned)(newlab + 1);
      }
    }
  }
  __syncthreads();

  // ---- Phase B: totals + cutoff bins ----
  if (tid < 128) {
    int s = 0;
    for (int b = tid * 16; b < tid * 16 + 16; ++b) s += g_hist[0][b];
    s_csp[tid] = s;
  } else if (tid < 256) {
    int t2 = tid - 128, s = 0;
    for (int b = t2 * 16; b < t2 * 16 + 16; ++b) s += g_hist[1][b];
    s_csn[t2] = s;
  }
  if (tid < 2) s_cnt[tid] = 0;
  __syncthreads();
  if (tid == 0) {
    int total_p = 0, total_n = 0;
    for (int c = 0; c < 128; ++c) { total_p += s_csp[c]; total_n += s_csn[c]; }
    int cur_pos = total_p < MAX_POSK ? total_p : MAX_POSK;
    int rem = TOTALK - cur_pos;
    int cur_neg = total_n < rem ? total_n : rem;
    s_cur[0] = cur_pos;
    s_cur[1] = cur_neg;
    s_cut[0] = find_cut(s_csp, g_hist[0], cur_pos);
    s_cut[1] = find_cut(s_csn, g_hist[1], cur_neg);
  }
  __syncthreads();

  // ---- Phase C: compact candidates into LDS ----
  const int cut0 = s_cut[0], cut1 = s_cut[1];
  for (int i = tid; i < N_ANCH; i += 1024) {
    const unsigned p = g_packed[i];
    const int lab0 = (int)(p & 3u);
    if (lab0 == 0) continue;                  // label -1
    const int s = (lab0 == 2) ? 0 : 1;
    if ((int)(p >> 21) >= (s == 0 ? cut0 : cut1)) {
      int q = atomicAdd(&s_cnt[s], 1);
      if (q < CAP)
        s_keys[s][q] = ((unsigned long long)(p >> 9) << 32) | (unsigned)(~i);
    }
  }
  // init selection + outputs while counts settle
  for (int t = tid; t < TOTALK; t += 1024) s_sel[t] = -1;
  for (int t = tid; t < 3 * TOTALK; t += 1024) out[t] = -1;
  __syncthreads();

  // ---- Phase D: rank-write (rank = #keys greater; unique by idx tiebreak) ----
  const int cur_pos = s_cur[0], cur_neg = s_cur[1];
  if (tid == 0) out[3 * TOTALK] = cur_pos;
  int Cp = s_cnt[0]; if (Cp > CAP) Cp = CAP;
  int Cn = s_cnt[1]; if (Cn > CAP) Cn = CAP;
  for (int t = tid; t < Cp; t += 1024) {
    unsigned long long me = s_keys[0][t];
    int r = 0;
    for (int u = 0; u < Cp; ++u) r += (s_keys[0][u] > me);
    if (r < cur_pos) {
      int idx = (int)(~(unsigned)me);
      s_sel[r] = idx;
      out[r] = idx;
      out[TOTALK + r] = 1;
    }
  }
  for (int t = tid; t < Cn; t += 1024) {
    unsigned long long me = s_keys[1][t];
    int r = 0;
    for (int u = 0; u < Cn; ++u) r += (s_keys[1][u] > me);
    if (r < cur_neg) {
      int idx = (int)(~(unsigned)me);
      s_sel[cur_pos + r] = idx;
      out[cur_pos + r] = idx;
      out[TOTALK + cur_pos + r] = 0;
    }
  }
  __syncthreads();

  // ---- Phase E: argmax for selected slots (IEEE f32 div, first-max) ----
  {
    const int slot = tid >> 2;                // 0..255
    const int q    = tid & 3;                 // GT quarter
    const int idx  = s_sel[slot];
    const int safe = idx < 0 ? 0 : idx;
    const float4 a = anchors[safe];
    const float A = (a.z - a.x) * (a.w - a.y);
    unsigned long long key = 0ULL;
    for (int k = 0; k < 64; ++k) {
      const int j = q * 64 + k;
      const float4 b = gt[j];
      const float B = (b.z - b.x) * (b.w - b.y);
      float ih = fmaxf(fminf(a.z, b.z) - fmaxf(a.x, b.x), 0.0f);
      float iw = fmaxf(fminf(a.w, b.w) - fmaxf(a.y, b.y), 0.0f);
      float inter = ih * iw;
      float uni = (A + B) - inter;
      float iou = inter / fmaxf(uni, 1e-8f);  // IEEE-exact, matches reference
      unsigned long long kk =
          ((unsigned long long)__float_as_uint(iou) << 32) | (unsigned)(~j);
      key = kk > key ? kk : key;
    }
    unsigned long long o1 = shfl_xor_u64(key, 1); key = o1 > key ? o1 : key;
    unsigned long long o2 = shfl_xor_u64(key, 2); key = o2 > key ? o2 : key;
    if (q == 0 && idx >= 0)
      out[2 * TOTALK + slot] = (int)(~(unsigned)key) & 0xFF;
  }
  __syncthreads();

  // ---- Phase F: cleanup for the next call (replaces k_init) ----
  for (int t = tid; t < 2 * NBINS; t += 1024) (&g_hist[0][0])[t] = 0;
  if (tid == 0) g_nbord = 0;
}

// ---------------------------------------------------------------------------
extern "C" void kernel_launch(void* const* d_in, const int* in_sizes, int n_in,
                              void* d_out, int out_size, void* d_ws, size_t ws_size,
                              hipStream_t stream) {
  (void)in_sizes; (void)n_in; (void)out_size; (void)d_ws; (void)ws_size;
  const float4* anchors = (const float4*)d_in[0];
  const float4* gt      = (const float4*)d_in[1];
  const int*    ph      = (const int*)d_in[2];
  const int*    pw      = (const int*)d_in[3];
  int*          out     = (int*)d_out;

  k_main<<<N_ANCH / 512, 256, 0, stream>>>(anchors, gt, ph, pw);
  k_tail<<<1, 1024, 0, stream>>>(anchors, gt, out);
}

// Round 6
// 139.631 us; speedup vs baseline: 1.5617x; 1.5617x over previous
//
#include <hip/hip_runtime.h>

// Forbid FMA contraction: the reference evaluates each f32 op separately; a
// fused (A+B) - ih*iw would change rounding and can flip labels at 0.3/0.7.
#pragma clang fp contract(off)

#define N_ANCH   262144
#define N_GT     256
#define MAX_POSK 128
#define TOTALK   256
#define NBINS    2048
#define CAP      2048      // filtered candidate LDS cap (actual ~300)
#define BORDCAP  2048
#define CAP_P    32768     // raw positive buffer
#define CAP_N    4096      // raw negative buffer (bin >= T_N)
#define T_N      2032      // top-16-bins prefilter for negatives

// ---------------------------------------------------------------------------
// Threefry-2x32 (exact JAX PRNG). 20 rounds — VERIFIED bit-exact (R2-R5).
// ---------------------------------------------------------------------------
struct TF2 { unsigned a, b; };

__host__ __device__ constexpr unsigned rotl32(unsigned v, int d) {
  return (v << d) | (v >> (32 - d));
}

__host__ __device__ constexpr TF2 tf2x32(unsigned k0, unsigned k1,
                                         unsigned x0, unsigned x1) {
  unsigned ks2 = k0 ^ k1 ^ 0x1BD11BDAu;
  x0 += k0; x1 += k1;
  x0 += x1; x1 = rotl32(x1, 13); x1 ^= x0;
  x0 += x1; x1 = rotl32(x1, 15); x1 ^= x0;
  x0 += x1; x1 = rotl32(x1, 26); x1 ^= x0;
  x0 += x1; x1 = rotl32(x1,  6); x1 ^= x0;
  x0 += k1; x1 += ks2 + 1u;
  x0 += x1; x1 = rotl32(x1, 17); x1 ^= x0;
  x0 += x1; x1 = rotl32(x1, 29); x1 ^= x0;
  x0 += x1; x1 = rotl32(x1, 16); x1 ^= x0;
  x0 += x1; x1 = rotl32(x1, 24); x1 ^= x0;
  x0 += ks2; x1 += k0 + 2u;
  x0 += x1; x1 = rotl32(x1, 13); x1 ^= x0;
  x0 += x1; x1 = rotl32(x1, 15); x1 ^= x0;
  x0 += x1; x1 = rotl32(x1, 26); x1 ^= x0;
  x0 += x1; x1 = rotl32(x1,  6); x1 ^= x0;
  x0 += k0; x1 += k1 + 3u;
  x0 += x1; x1 = rotl32(x1, 17); x1 ^= x0;
  x0 += x1; x1 = rotl32(x1, 29); x1 ^= x0;
  x0 += x1; x1 = rotl32(x1, 16); x1 ^= x0;
  x0 += x1; x1 = rotl32(x1, 24); x1 ^= x0;
  x0 += k1; x1 += ks2 + 4u;
  x0 += x1; x1 = rotl32(x1, 13); x1 ^= x0;
  x0 += x1; x1 = rotl32(x1, 15); x1 ^= x0;
  x0 += x1; x1 = rotl32(x1, 26); x1 ^= x0;
  x0 += x1; x1 = rotl32(x1,  6); x1 ^= x0;
  x0 += ks2; x1 += k0 + 5u;
  return TF2{x0, x1};
}

// jax.random.key(42); partitionable threefry (verified):
//   split: child i = both words of E(key,(0,i));  bits[i] = E(key,(0,i)).a ^ .b
constexpr unsigned KP0 = tf2x32(0u, 42u, 0u, 0u).a;
constexpr unsigned KP1 = tf2x32(0u, 42u, 0u, 0u).b;
constexpr unsigned KN0 = tf2x32(0u, 42u, 0u, 1u).a;
constexpr unsigned KN1 = tf2x32(0u, 42u, 0u, 1u).b;

__device__ inline unsigned score_bits(unsigned k0, unsigned k1, unsigned i) {
  TF2 r = tf2x32(k0, k1, 0u, i);
  return r.a ^ r.b;
}

// Exact threshold constants (verified R3-R5):
// round32(q) > 0.7f  <=> q >= MPOSD ;  round32(q) >= 0.3f <=> q >= MNEGD
constexpr double MPOSD = (double)0.7f + 0x1p-25;
constexpr double MNEGD = (double)0.3f - 0x1p-26;
// inter >= m*(A+B-inter) <=> inter >= [m/(1+m)]*(A+B)
constexpr float CPF = (float)(MPOSD / (1.0 + MPOSD));
constexpr float CNF = (float)(MNEGD / (1.0 + MNEGD));

// ---------------------------------------------------------------------------
// Device-global scratch. Histograms/counters are zero at entry to k_main on
// EVERY call: zero-init at module load, re-zeroed by k_tail's cleanup phase
// each launch (harness only poisons d_out/d_ws; graph replays are complete).
// ---------------------------------------------------------------------------
__device__ unsigned g_packed[N_ANCH];   // (sbits & ~511) | (label+1)
__device__ int      g_hist[2][NBINS];
__device__ int      g_nbord;
__device__ int      g_bord[BORDCAP];
__device__ int      g_cntp, g_cntn;
__device__ int      g_cand_p[CAP_P];    // anchor idx, all positives
__device__ int      g_cand_n[CAP_N];    // anchor idx, negatives with bin >= T_N

// ---------------------------------------------------------------------------
__device__ inline void finish_anchor(int i, float4 a, float mp, float mn,
                                     float Hf, float Wf) {
  const float A = (a.z - a.x) * (a.w - a.y);
  const float mrp = mp - CPF * A;     // sign == sign of best q vs MPOSD (+/- band)
  const float mrn = mn - CNF * A;
  const bool inside = (a.x >= 0.0f) && (a.y >= 0.0f) && (a.z <= Hf) && (a.w <= Wf);
  // rounding-error bound ~6*2^-24*(A+B); band = 12*2^-24*(A+65536) >= 2x slack
  const float band = 0x1.8p-21f * (A + 65536.0f);
  const bool pos = mrp > band;
  const bool nny = mrn > band;
  int lab = pos ? 1 : (nny ? -1 : 0);
  if (!inside) lab = -1;

  unsigned sb = 0u;
  if (lab >= 0) {
    sb = score_bits(lab == 1 ? KP0 : KN0, lab == 1 ? KP1 : KN1, (unsigned)i);
    atomicAdd(&g_hist[lab == 1 ? 0 : 1][sb >> 21], 1);
    if (lab == 1) {
      int q = atomicAdd(&g_cntp, 1);
      if (q < CAP_P) g_cand_p[q] = i;
    } else if ((sb >> 21) >= T_N) {
      int q = atomicAdd(&g_cntn, 1);
      if (q < CAP_N) g_cand_n[q] = i;
    }
  }
  g_packed[i] = (sb & ~511u) | (unsigned)(lab + 1);

  if (inside && (fabsf(mrp) <= band || fabsf(mrn) <= band)) {
    int b = atomicAdd(&g_nbord, 1);
    if (b < BORDCAP) g_bord[b] = i;
  }
}

// 2 anchors/thread: 256 division-free IoU threshold tests each, score + hist.
// (Math byte-identical to the R4/R5-verified version.)
__global__ __launch_bounds__(256) void k_main(const float4* __restrict__ anchors,
                                              const float4* __restrict__ gt,
                                              const int* __restrict__ ph,
                                              const int* __restrict__ pw) {
  __shared__ float4 s_gt[N_GT];
  __shared__ float  s_tp[N_GT];   // CPF * B_j
  __shared__ float  s_tn[N_GT];   // CNF * B_j
  const int tid = threadIdx.x;
  {
    float4 g = gt[tid];
    s_gt[tid] = g;
    float B = (g.z - g.x) * (g.w - g.y);
    s_tp[tid] = CPF * B;
    s_tn[tid] = CNF * B;
  }
  __syncthreads();

  const int i0 = blockIdx.x * 512 + tid;
  const int i1 = i0 + 256;
  const float4 a0 = anchors[i0];
  const float4 a1 = anchors[i1];
  const float Hf = (float)(*ph);
  const float Wf = (float)(*pw);

  float mp0 = -1e30f, mn0 = -1e30f, mp1 = -1e30f, mn1 = -1e30f;
  #pragma unroll 4
  for (int j = 0; j < N_GT; ++j) {
    const float4 b = s_gt[j];
    const float tp = s_tp[j];
    const float tn = s_tn[j];
    float ih0 = fmaxf(fminf(a0.z, b.z) - fmaxf(a0.x, b.x), 0.0f);
    float iw0 = fmaxf(fminf(a0.w, b.w) - fmaxf(a0.y, b.y), 0.0f);
    float in0 = ih0 * iw0;
    mp0 = fmaxf(mp0, in0 - tp);
    mn0 = fmaxf(mn0, in0 - tn);
    float ih1 = fmaxf(fminf(a1.z, b.z) - fmaxf(a1.x, b.x), 0.0f);
    float iw1 = fmaxf(fminf(a1.w, b.w) - fmaxf(a1.y, b.y), 0.0f);
    float in1 = ih1 * iw1;
    mp1 = fmaxf(mp1, in1 - tp);
    mn1 = fmaxf(mn1, in1 - tn);
  }
  finish_anchor(i0, a0, mp0, mn0, Hf, Wf);
  finish_anchor(i1, a1, mp1, mn1, Hf, Wf);
}

__device__ int find_cut(const int* cs, const int* hist, int K) {
  if (K <= 0) return NBINS;
  int suffix = 0, c = 127;
  for (; c >= 0; --c) {
    if (suffix + cs[c] >= K) break;
    suffix += cs[c];
  }
  if (c < 0) return 0;
  for (int b = c * 16 + 15; b >= c * 16; --b) {
    suffix += hist[b];
    if (suffix >= K) return b;
  }
  return c * 16;
}

__device__ inline unsigned long long shfl_xor_u64(unsigned long long v, int m) {
  unsigned lo = (unsigned)v, hi = (unsigned)(v >> 32);
  lo = __shfl_xor(lo, m, 64);
  hi = __shfl_xor(hi, m, 64);
  return ((unsigned long long)hi << 32) | lo;
}

// Fused tail: border-resolve -> cuts -> compact-from-buffers -> rank-write ->
// argmax -> cleanup. One block, 1024 threads. No full-array scans.
__global__ __launch_bounds__(1024) void k_tail(const float4* __restrict__ anchors,
                                               const float4* __restrict__ gt,
                                               int* __restrict__ out) {
  __shared__ unsigned long long s_keys[2][CAP];   // (score23<<32)|~idx, filtered
  __shared__ int s_csp[128], s_csn[128];
  __shared__ int s_sel[TOTALK];
  __shared__ int s_cut[2], s_cnt[2], s_cur[2], s_full;
  const int tid  = threadIdx.x;
  const int wid  = tid >> 6, lane = tid & 63;

  // ---- Phase A: border resolve (one anchor per wave, exact f64 compares) ----
  int nb = g_nbord; if (nb > BORDCAP) nb = BORDCAP;
  for (int b = wid; b < nb; b += 16) {
    const int i = g_bord[b];
    const float4 a = anchors[i];
    const float A = (a.z - a.x) * (a.w - a.y);
    bool p = false, nn = false;
    #pragma unroll
    for (int k = 0; k < 4; ++k) {
      const int j = lane + 64 * k;
      float4 bb = gt[j];
      float ih = fmaxf(fminf(a.z, bb.z) - fmaxf(a.x, bb.x), 0.0f);
      float iw = fmaxf(fminf(a.w, bb.w) - fmaxf(a.y, bb.y), 0.0f);
      float inter = ih * iw;
      float Bar = (bb.z - bb.x) * (bb.w - bb.y);
      float uni = (A + Bar) - inter;          // exact reference f32 rounding
      double id = (double)inter, ud = (double)uni;
      p  |= (id >= MPOSD * ud);               // exact: 25x24-bit products in f64
      nn |= (id >= MNEGD * ud);
    }
    unsigned long long bp = __ballot(p);
    unsigned long long bn = __ballot(nn);
    if (lane == 0) {
      int newlab = bp ? 1 : (bn ? -1 : 0);
      unsigned old = g_packed[i];
      int oldlab = (int)(old & 3u) - 1;
      if (newlab != oldlab) {
        if (oldlab >= 0) atomicAdd(&g_hist[oldlab == 1 ? 0 : 1][old >> 21], -1);
        unsigned sb = 0u;
        if (newlab >= 0) {
          sb = score_bits(newlab == 1 ? KP0 : KN0, newlab == 1 ? KP1 : KN1, (unsigned)i);
          atomicAdd(&g_hist[newlab == 1 ? 0 : 1][sb >> 21], 1);
          if (newlab == 1) {                   // same append rules as k_main
            int q = atomicAdd(&g_cntp, 1);
            if (q < CAP_P) g_cand_p[q] = i;
          } else if ((sb >> 21) >= T_N) {
            int q = atomicAdd(&g_cntn, 1);
            if (q < CAP_N) g_cand_n[q] = i;
          }
        }
        g_packed[i] = (sb & ~511u) | (unsigned)(newlab + 1);
      }
    }
  }
  __syncthreads();

  // ---- Phase B: totals + cutoff bins ----
  if (tid < 128) {
    int s = 0;
    for (int b = tid * 16; b < tid * 16 + 16; ++b) s += g_hist[0][b];
    s_csp[tid] = s;
  } else if (tid < 256) {
    int t2 = tid - 128, s = 0;
    for (int b = t2 * 16; b < t2 * 16 + 16; ++b) s += g_hist[1][b];
    s_csn[t2] = s;
  }
  if (tid < 2) s_cnt[tid] = 0;
  __syncthreads();
  if (tid == 0) {
    int total_p = 0, total_n = 0;
    for (int c = 0; c < 128; ++c) { total_p += s_csp[c]; total_n += s_csn[c]; }
    int cur_pos = total_p < MAX_POSK ? total_p : MAX_POSK;
    int rem = TOTALK - cur_pos;
    int cur_neg = total_n < rem ? total_n : rem;
    s_cur[0] = cur_pos;
    s_cur[1] = cur_neg;
    s_cut[0] = find_cut(s_csp, g_hist[0], cur_pos);
    s_cut[1] = find_cut(s_csn, g_hist[1], cur_neg);
    // Exact safety: buffer path valid iff no overflow and cut_n >= T_N
    // (cut_n >= T_N holds whenever suffix(T_N) >= cur_neg; ~24 sigma margin).
    s_full = (g_cntp > CAP_P) || (g_cntn > CAP_N) ||
             (cur_neg > 0 && s_cut[1] < T_N);
  }
  __syncthreads();

  // ---- Phase C: compact candidates into LDS (from small buffers) ----
  const int cut0 = s_cut[0], cut1 = s_cut[1];
  if (!s_full) {
    int Cp = g_cntp;                          // <= CAP_P (checked)
    for (int t = tid; t < Cp; t += 1024) {
      const int i = g_cand_p[t];
      const unsigned p = g_packed[i];         // re-read: honors border flips
      if ((p & 3u) == 2u && (int)(p >> 21) >= cut0) {
        int q = atomicAdd(&s_cnt[0], 1);
        if (q < CAP)
          s_keys[0][q] = ((unsigned long long)(p >> 9) << 32) | (unsigned)(~i);
      }
    }
    int Cn = g_cntn;
    for (int t = tid; t < Cn; t += 1024) {
      const int i = g_cand_n[t];
      const unsigned p = g_packed[i];
      if ((p & 3u) == 1u && (int)(p >> 21) >= cut1) {
        int q = atomicAdd(&s_cnt[1], 1);
        if (q < CAP)
          s_keys[1][q] = ((unsigned long long)(p >> 9) << 32) | (unsigned)(~i);
      }
    }
  } else {
    // Never-triggered exact fallback: full scan (slow, single block).
    for (int i = tid; i < N_ANCH; i += 1024) {
      const unsigned p = g_packed[i];
      const int lab0 = (int)(p & 3u);
      if (lab0 == 0) continue;
      const int s = (lab0 == 2) ? 0 : 1;
      if ((int)(p >> 21) >= (s == 0 ? cut0 : cut1)) {
        int q = atomicAdd(&s_cnt[s], 1);
        if (q < CAP)
          s_keys[s][q] = ((unsigned long long)(p >> 9) << 32) | (unsigned)(~i);
      }
    }
  }
  for (int t = tid; t < TOTALK; t += 1024) s_sel[t] = -1;
  for (int t = tid; t < 3 * TOTALK; t += 1024) out[t] = -1;
  __syncthreads();

  // ---- Phase D: rank-write (rank = #keys greater; unique by idx tiebreak) ----
  const int cur_pos = s_cur[0], cur_neg = s_cur[1];
  if (tid == 0) out[3 * TOTALK] = cur_pos;
  int Cp = s_cnt[0]; if (Cp > CAP) Cp = CAP;
  int Cn = s_cnt[1]; if (Cn > CAP) Cn = CAP;
  for (int t = tid; t < Cp; t += 1024) {
    unsigned long long me = s_keys[0][t];
    int r = 0;
    for (int u = 0; u < Cp; ++u) r += (s_keys[0][u] > me);
    if (r < cur_pos) {
      int idx = (int)(~(unsigned)me);
      s_sel[r] = idx;
      out[r] = idx;
      out[TOTALK + r] = 1;
    }
  }
  for (int t = tid; t < Cn; t += 1024) {
    unsigned long long me = s_keys[1][t];
    int r = 0;
    for (int u = 0; u < Cn; ++u) r += (s_keys[1][u] > me);
    if (r < cur_neg) {
      int idx = (int)(~(unsigned)me);
      s_sel[cur_pos + r] = idx;
      out[cur_pos + r] = idx;
      out[TOTALK + cur_pos + r] = 0;
    }
  }
  __syncthreads();

  // ---- Phase E: argmax for selected slots (IEEE f32 div, first-max) ----
  {
    const int slot = tid >> 2;                // 0..255
    const int q    = tid & 3;                 // GT quarter
    const int idx  = s_sel[slot];
    const int safe = idx < 0 ? 0 : idx;
    const float4 a = anchors[safe];
    const float A = (a.z - a.x) * (a.w - a.y);
    unsigned long long key = 0ULL;
    for (int k = 0; k < 64; ++k) {
      const int j = q * 64 + k;
      const float4 b = gt[j];
      const float B = (b.z - b.x) * (b.w - b.y);
      float ih = fmaxf(fminf(a.z, b.z) - fmaxf(a.x, b.x), 0.0f);
      float iw = fmaxf(fminf(a.w, b.w) - fmaxf(a.y, b.y), 0.0f);
      float inter = ih * iw;
      float uni = (A + B) - inter;
      float iou = inter / fmaxf(uni, 1e-8f);  // IEEE-exact, matches reference
      unsigned long long kk =
          ((unsigned long long)__float_as_uint(iou) << 32) | (unsigned)(~j);
      key = kk > key ? kk : key;
    }
    unsigned long long o1 = shfl_xor_u64(key, 1); key = o1 > key ? o1 : key;
    unsigned long long o2 = shfl_xor_u64(key, 2); key = o2 > key ? o2 : key;
    if (q == 0 && idx >= 0)
      out[2 * TOTALK + slot] = (int)(~(unsigned)key) & 0xFF;
  }
  __syncthreads();

  // ---- Phase F: cleanup for the next call ----
  for (int t = tid; t < 2 * NBINS; t += 1024) (&g_hist[0][0])[t] = 0;
  if (tid == 0) { g_nbord = 0; g_cntp = 0; g_cntn = 0; }
}

// ---------------------------------------------------------------------------
extern "C" void kernel_launch(void* const* d_in, const int* in_sizes, int n_in,
                              void* d_out, int out_size, void* d_ws, size_t ws_size,
                              hipStream_t stream) {
  (void)in_sizes; (void)n_in; (void)out_size; (void)d_ws; (void)ws_size;
  const float4* anchors = (const float4*)d_in[0];
  const float4* gt      = (const float4*)d_in[1];
  const int*    ph      = (const int*)d_in[2];
  const int*    pw      = (const int*)d_in[3];
  int*          out     = (int*)d_out;

  k_main<<<N_ANCH / 512, 256, 0, stream>>>(anchors, gt, ph, pw);
  k_tail<<<1, 1024, 0, stream>>>(anchors, gt, out);
}

// Round 7
// 126.482 us; speedup vs baseline: 1.7240x; 1.1040x over previous
//
#include <hip/hip_runtime.h>

// Forbid FMA contraction: the reference evaluates each f32 op separately; a
// fused (A+B) - ih*iw would change rounding and can flip labels at 0.3/0.7.
#pragma clang fp contract(off)

#define N_ANCH   262144
#define N_GT     256
#define MAX_POSK 128
#define TOTALK   256
#define NBINS    2048
#define CAP      2048      // filtered candidate LDS cap (actual ~300)
#define BORDCAP  2048
#define CAP_P    32768     // raw positive buffer
#define CAP_N    4096      // raw negative buffer (bin >= T_N)
#define T_N      2032      // top-16-bins prefilter for negatives

// ---------------------------------------------------------------------------
// Threefry-2x32 (exact JAX PRNG). 20 rounds — VERIFIED bit-exact (R2-R6).
// ---------------------------------------------------------------------------
struct TF2 { unsigned a, b; };

__host__ __device__ constexpr unsigned rotl32(unsigned v, int d) {
  return (v << d) | (v >> (32 - d));
}

__host__ __device__ constexpr TF2 tf2x32(unsigned k0, unsigned k1,
                                         unsigned x0, unsigned x1) {
  unsigned ks2 = k0 ^ k1 ^ 0x1BD11BDAu;
  x0 += k0; x1 += k1;
  x0 += x1; x1 = rotl32(x1, 13); x1 ^= x0;
  x0 += x1; x1 = rotl32(x1, 15); x1 ^= x0;
  x0 += x1; x1 = rotl32(x1, 26); x1 ^= x0;
  x0 += x1; x1 = rotl32(x1,  6); x1 ^= x0;
  x0 += k1; x1 += ks2 + 1u;
  x0 += x1; x1 = rotl32(x1, 17); x1 ^= x0;
  x0 += x1; x1 = rotl32(x1, 29); x1 ^= x0;
  x0 += x1; x1 = rotl32(x1, 16); x1 ^= x0;
  x0 += x1; x1 = rotl32(x1, 24); x1 ^= x0;
  x0 += ks2; x1 += k0 + 2u;
  x0 += x1; x1 = rotl32(x1, 13); x1 ^= x0;
  x0 += x1; x1 = rotl32(x1, 15); x1 ^= x0;
  x0 += x1; x1 = rotl32(x1, 26); x1 ^= x0;
  x0 += x1; x1 = rotl32(x1,  6); x1 ^= x0;
  x0 += k0; x1 += k1 + 3u;
  x0 += x1; x1 = rotl32(x1, 17); x1 ^= x0;
  x0 += x1; x1 = rotl32(x1, 29); x1 ^= x0;
  x0 += x1; x1 = rotl32(x1, 16); x1 ^= x0;
  x0 += x1; x1 = rotl32(x1, 24); x1 ^= x0;
  x0 += k1; x1 += ks2 + 4u;
  x0 += x1; x1 = rotl32(x1, 13); x1 ^= x0;
  x0 += x1; x1 = rotl32(x1, 15); x1 ^= x0;
  x0 += x1; x1 = rotl32(x1, 26); x1 ^= x0;
  x0 += x1; x1 = rotl32(x1,  6); x1 ^= x0;
  x0 += ks2; x1 += k0 + 5u;
  return TF2{x0, x1};
}

// jax.random.key(42); partitionable threefry (verified):
//   split: child i = both words of E(key,(0,i));  bits[i] = E(key,(0,i)).a ^ .b
constexpr unsigned KP0 = tf2x32(0u, 42u, 0u, 0u).a;
constexpr unsigned KP1 = tf2x32(0u, 42u, 0u, 0u).b;
constexpr unsigned KN0 = tf2x32(0u, 42u, 0u, 1u).a;
constexpr unsigned KN1 = tf2x32(0u, 42u, 0u, 1u).b;

__device__ inline unsigned score_bits(unsigned k0, unsigned k1, unsigned i) {
  TF2 r = tf2x32(k0, k1, 0u, i);
  return r.a ^ r.b;
}

// Exact threshold constants (verified R3-R6):
// round32(q) > 0.7f  <=> q >= MPOSD ;  round32(q) >= 0.3f <=> q >= MNEGD
constexpr double MPOSD = (double)0.7f + 0x1p-25;
constexpr double MNEGD = (double)0.3f - 0x1p-26;
// inter >= m*(A+B-inter) <=> inter >= [m/(1+m)]*(A+B)
constexpr float CPF = (float)(MPOSD / (1.0 + MPOSD));
constexpr float CNF = (float)(MNEGD / (1.0 + MNEGD));

// ---------------------------------------------------------------------------
// Device-global scratch. Histograms/counters are zero at entry to k_main on
// EVERY call: zero-init at module load, re-zeroed by k_tail's cleanup phase
// each launch (harness only poisons d_out/d_ws; graph replays are complete).
// ---------------------------------------------------------------------------
__device__ unsigned g_packed[N_ANCH];   // (sbits & ~511) | (label+1)
__device__ int      g_hist[2][NBINS];
__device__ int      g_nbord;
__device__ int      g_bord[BORDCAP];
__device__ int      g_cntp, g_cntn;
__device__ int      g_cand_p[CAP_P];    // anchor idx, all positives
__device__ int      g_cand_n[CAP_N];    // anchor idx, negatives with bin >= T_N

// ---------------------------------------------------------------------------
__device__ inline void finish_anchor(int i, float4 a, float mp, float mn,
                                     float Hf, float Wf) {
  const float A = (a.z - a.x) * (a.w - a.y);
  const float mrp = mp - CPF * A;     // sign == sign of best q vs MPOSD (+/- band)
  const float mrn = mn - CNF * A;
  const bool inside = (a.x >= 0.0f) && (a.y >= 0.0f) && (a.z <= Hf) && (a.w <= Wf);
  // rounding-error bound ~6*2^-24*(A+B); band = 12*2^-24*(A+65536) >= 2x slack
  const float band = 0x1.8p-21f * (A + 65536.0f);
  const bool pos = mrp > band;
  const bool nny = mrn > band;
  int lab = pos ? 1 : (nny ? -1 : 0);
  if (!inside) lab = -1;

  unsigned sb = 0u;
  if (lab >= 0) {
    sb = score_bits(lab == 1 ? KP0 : KN0, lab == 1 ? KP1 : KN1, (unsigned)i);
    atomicAdd(&g_hist[lab == 1 ? 0 : 1][sb >> 21], 1);
    if (lab == 1) {
      int q = atomicAdd(&g_cntp, 1);
      if (q < CAP_P) g_cand_p[q] = i;
    } else if ((sb >> 21) >= T_N) {
      int q = atomicAdd(&g_cntn, 1);
      if (q < CAP_N) g_cand_n[q] = i;
    }
  }
  g_packed[i] = (sb & ~511u) | (unsigned)(lab + 1);

  if (inside && (fabsf(mrp) <= band || fabsf(mrn) <= band)) {
    int b = atomicAdd(&g_nbord, 1);
    if (b < BORDCAP) g_bord[b] = i;
  }
}

// 2 anchors/thread: 256 division-free IoU threshold tests each, score + hist.
// (Math byte-identical to the R4-R6 verified version.)
__global__ __launch_bounds__(256) void k_main(const float4* __restrict__ anchors,
                                              const float4* __restrict__ gt,
                                              const int* __restrict__ ph,
                                              const int* __restrict__ pw) {
  __shared__ float4 s_gt[N_GT];
  __shared__ float  s_tp[N_GT];   // CPF * B_j
  __shared__ float  s_tn[N_GT];   // CNF * B_j
  const int tid = threadIdx.x;
  {
    float4 g = gt[tid];
    s_gt[tid] = g;
    float B = (g.z - g.x) * (g.w - g.y);
    s_tp[tid] = CPF * B;
    s_tn[tid] = CNF * B;
  }
  __syncthreads();

  const int i0 = blockIdx.x * 512 + tid;
  const int i1 = i0 + 256;
  const float4 a0 = anchors[i0];
  const float4 a1 = anchors[i1];
  const float Hf = (float)(*ph);
  const float Wf = (float)(*pw);

  float mp0 = -1e30f, mn0 = -1e30f, mp1 = -1e30f, mn1 = -1e30f;
  #pragma unroll 4
  for (int j = 0; j < N_GT; ++j) {
    const float4 b = s_gt[j];
    const float tp = s_tp[j];
    const float tn = s_tn[j];
    float ih0 = fmaxf(fminf(a0.z, b.z) - fmaxf(a0.x, b.x), 0.0f);
    float iw0 = fmaxf(fminf(a0.w, b.w) - fmaxf(a0.y, b.y), 0.0f);
    float in0 = ih0 * iw0;
    mp0 = fmaxf(mp0, in0 - tp);
    mn0 = fmaxf(mn0, in0 - tn);
    float ih1 = fmaxf(fminf(a1.z, b.z) - fmaxf(a1.x, b.x), 0.0f);
    float iw1 = fmaxf(fminf(a1.w, b.w) - fmaxf(a1.y, b.y), 0.0f);
    float in1 = ih1 * iw1;
    mp1 = fmaxf(mp1, in1 - tp);
    mn1 = fmaxf(mn1, in1 - tn);
  }
  finish_anchor(i0, a0, mp0, mn0, Hf, Wf);
  finish_anchor(i1, a1, mp1, mn1, Hf, Wf);
}

__device__ inline unsigned long long shfl_xor_u64(unsigned long long v, int m) {
  unsigned lo = (unsigned)v, hi = (unsigned)(v >> 32);
  lo = __shfl_xor(lo, m, 64);
  hi = __shfl_xor(hi, m, 64);
  return ((unsigned long long)hi << 32) | lo;
}

// Fused tail: hist->LDS -> border-resolve -> parallel totals/cuts ->
// compact-from-buffers -> rank-write -> argmax -> cleanup.
// One block, 1024 threads. No single-thread serial scans, no full-array scans.
__global__ __launch_bounds__(1024) void k_tail(const float4* __restrict__ anchors,
                                               const float4* __restrict__ gt,
                                               int* __restrict__ out) {
  __shared__ unsigned long long s_keys[2][CAP];   // 32 KB: (score23<<32)|~idx
  __shared__ int    s_hist[2][NBINS];             // 16 KB: LDS copy of g_hist
  __shared__ float4 s_gt[N_GT];                   //  4 KB
  __shared__ int    s_cs[2][128];                 // chunk sums (16 bins each)
  __shared__ int    s_sx[2][128];                 // exclusive suffix of chunks
  __shared__ int    s_sel[TOTALK];
  __shared__ int    s_cut[2], s_cnt[2], s_cur[2], s_full;
  const int tid  = threadIdx.x;
  const int wid  = tid >> 6, lane = tid & 63;

  // ---- Phase 0: stage gt + hist into LDS (coalesced) ----
  for (int t = tid; t < N_GT; t += 1024) s_gt[t] = gt[t];
  for (int t = tid; t < 2 * NBINS; t += 1024)
    (&s_hist[0][0])[t] = (&g_hist[0][0])[t];
  if (tid < 2) s_cnt[tid] = 0;
  __syncthreads();

  // ---- Phase A: border resolve (one anchor per wave, exact f64 compares) ----
  int nb = g_nbord; if (nb > BORDCAP) nb = BORDCAP;
  for (int b = wid; b < nb; b += 16) {
    const int i = g_bord[b];
    const float4 a = anchors[i];
    const float A = (a.z - a.x) * (a.w - a.y);
    bool p = false, nn = false;
    #pragma unroll
    for (int k = 0; k < 4; ++k) {
      const int j = lane + 64 * k;
      float4 bb = s_gt[j];
      float ih = fmaxf(fminf(a.z, bb.z) - fmaxf(a.x, bb.x), 0.0f);
      float iw = fmaxf(fminf(a.w, bb.w) - fmaxf(a.y, bb.y), 0.0f);
      float inter = ih * iw;
      float Bar = (bb.z - bb.x) * (bb.w - bb.y);
      float uni = (A + Bar) - inter;          // exact reference f32 rounding
      double id = (double)inter, ud = (double)uni;
      p  |= (id >= MPOSD * ud);               // exact: 25x24-bit products in f64
      nn |= (id >= MNEGD * ud);
    }
    unsigned long long bp = __ballot(p);
    unsigned long long bn = __ballot(nn);
    if (lane == 0) {
      int newlab = bp ? 1 : (bn ? -1 : 0);
      unsigned old = g_packed[i];
      int oldlab = (int)(old & 3u) - 1;
      if (newlab != oldlab) {
        if (oldlab >= 0) atomicAdd(&s_hist[oldlab == 1 ? 0 : 1][old >> 21], -1);
        unsigned sb = 0u;
        if (newlab >= 0) {
          sb = score_bits(newlab == 1 ? KP0 : KN0, newlab == 1 ? KP1 : KN1, (unsigned)i);
          atomicAdd(&s_hist[newlab == 1 ? 0 : 1][sb >> 21], 1);
          if (newlab == 1) {                   // same append rules as k_main
            int q = atomicAdd(&g_cntp, 1);
            if (q < CAP_P) g_cand_p[q] = i;
          } else if ((sb >> 21) >= T_N) {
            int q = atomicAdd(&g_cntn, 1);
            if (q < CAP_N) g_cand_n[q] = i;
          }
        }
        g_packed[i] = (sb & ~511u) | (unsigned)(newlab + 1);
      }
    }
  }
  __syncthreads();

  // ---- Phase B: parallel totals + cutoff bins (all from LDS) ----
  // B1: 16-bin chunk sums, 256 threads (cls = tid>>7, chunk = tid&127)
  if (tid < 256) {
    const int cls = tid >> 7, c = tid & 127;
    int s = 0;
    #pragma unroll
    for (int b = c * 16; b < c * 16 + 16; ++b) s += s_hist[cls][b];
    s_cs[cls][c] = s;
  }
  __syncthreads();
  // B2: brute-force exclusive suffix over chunks (pipelined LDS reads)
  if (tid < 256) {
    const int cls = tid >> 7, c = tid & 127;
    int s = 0;
    for (int c2 = c + 1; c2 < 128; ++c2) s += s_cs[cls][c2];
    s_sx[cls][c] = s;
  }
  __syncthreads();
  // B3: totals -> cur_pos/cur_neg
  if (tid == 0) {
    int total_p = s_sx[0][0] + s_cs[0][0];
    int total_n = s_sx[1][0] + s_cs[1][0];
    int cur_pos = total_p < MAX_POSK ? total_p : MAX_POSK;
    int rem = TOTALK - cur_pos;
    int cur_neg = total_n < rem ? total_n : rem;
    s_cur[0] = cur_pos;
    s_cur[1] = cur_neg;
    s_cut[0] = NBINS;          // default for K<=0; overwritten by owner chunk
    s_cut[1] = NBINS;
  }
  __syncthreads();
  // B4: cut = largest b with suffix(b) >= K; unique owner chunk writes it.
  // Identical semantics to the R3-R6 verified serial find_cut.
  if (tid < 256) {
    const int cls = tid >> 7, c = tid & 127;
    const int K = s_cur[cls];
    if (K > 0) {
      const int sx = s_sx[cls][c];
      if (sx < K && sx + s_cs[cls][c] >= K) {
        int suffix = sx;
        int cut = c * 16;
        for (int b = c * 16 + 15; b >= c * 16; --b) {
          suffix += s_hist[cls][b];
          if (suffix >= K) { cut = b; break; }
        }
        s_cut[cls] = cut;
      }
    }
  }
  __syncthreads();
  if (tid == 0) {
    // Exact safety: buffer path valid iff no overflow and cut_n >= T_N
    // (cut_n >= T_N holds whenever suffix(T_N) >= cur_neg; ~24 sigma margin).
    s_full = (g_cntp > CAP_P) || (g_cntn > CAP_N) ||
             (s_cur[1] > 0 && s_cut[1] < T_N);
  }
  __syncthreads();

  // ---- Phase C: compact candidates into LDS (from small buffers) ----
  const int cut0 = s_cut[0], cut1 = s_cut[1];
  if (!s_full) {
    int Cp = g_cntp;                          // <= CAP_P (checked)
    for (int t = tid; t < Cp; t += 1024) {
      const int i = g_cand_p[t];
      const unsigned p = g_packed[i];         // re-read: honors border flips
      if ((p & 3u) == 2u && (int)(p >> 21) >= cut0) {
        int q = atomicAdd(&s_cnt[0], 1);
        if (q < CAP)
          s_keys[0][q] = ((unsigned long long)(p >> 9) << 32) | (unsigned)(~i);
      }
    }
    int Cn = g_cntn;
    for (int t = tid; t < Cn; t += 1024) {
      const int i = g_cand_n[t];
      const unsigned p = g_packed[i];
      if ((p & 3u) == 1u && (int)(p >> 21) >= cut1) {
        int q = atomicAdd(&s_cnt[1], 1);
        if (q < CAP)
          s_keys[1][q] = ((unsigned long long)(p >> 9) << 32) | (unsigned)(~i);
      }
    }
  } else {
    // Never-triggered exact fallback: full scan (slow, single block).
    for (int i = tid; i < N_ANCH; i += 1024) {
      const unsigned p = g_packed[i];
      const int lab0 = (int)(p & 3u);
      if (lab0 == 0) continue;
      const int s = (lab0 == 2) ? 0 : 1;
      if ((int)(p >> 21) >= (s == 0 ? cut0 : cut1)) {
        int q = atomicAdd(&s_cnt[s], 1);
        if (q < CAP)
          s_keys[s][q] = ((unsigned long long)(p >> 9) << 32) | (unsigned)(~i);
      }
    }
  }
  for (int t = tid; t < TOTALK; t += 1024) s_sel[t] = -1;
  for (int t = tid; t < 3 * TOTALK; t += 1024) out[t] = -1;
  __syncthreads();

  // ---- Phase D: rank-write (rank = #keys greater; unique by idx tiebreak) ----
  const int cur_pos = s_cur[0], cur_neg = s_cur[1];
  if (tid == 0) out[3 * TOTALK] = cur_pos;
  int Cp = s_cnt[0]; if (Cp > CAP) Cp = CAP;
  int Cn = s_cnt[1]; if (Cn > CAP) Cn = CAP;
  for (int t = tid; t < Cp; t += 1024) {
    unsigned long long me = s_keys[0][t];
    int r = 0;
    for (int u = 0; u < Cp; ++u) r += (s_keys[0][u] > me);
    if (r < cur_pos) {
      int idx = (int)(~(unsigned)me);
      s_sel[r] = idx;
      out[r] = idx;
      out[TOTALK + r] = 1;
    }
  }
  for (int t = tid; t < Cn; t += 1024) {
    unsigned long long me = s_keys[1][t];
    int r = 0;
    for (int u = 0; u < Cn; ++u) r += (s_keys[1][u] > me);
    if (r < cur_neg) {
      int idx = (int)(~(unsigned)me);
      s_sel[cur_pos + r] = idx;
      out[cur_pos + r] = idx;
      out[TOTALK + cur_pos + r] = 0;
    }
  }
  __syncthreads();

  // ---- Phase E: argmax for selected slots (IEEE f32 div, first-max) ----
  {
    const int slot = tid >> 2;                // 0..255
    const int q    = tid & 3;                 // GT quarter
    const int idx  = s_sel[slot];
    const int safe = idx < 0 ? 0 : idx;
    const float4 a = anchors[safe];
    const float A = (a.z - a.x) * (a.w - a.y);
    unsigned long long key = 0ULL;
    for (int k = 0; k < 64; ++k) {
      const int j = q * 64 + k;
      const float4 b = s_gt[j];
      const float B = (b.z - b.x) * (b.w - b.y);
      float ih = fmaxf(fminf(a.z, b.z) - fmaxf(a.x, b.x), 0.0f);
      float iw = fmaxf(fminf(a.w, b.w) - fmaxf(a.y, b.y), 0.0f);
      float inter = ih * iw;
      float uni = (A + B) - inter;
      float iou = inter / fmaxf(uni, 1e-8f);  // IEEE-exact, matches reference
      unsigned long long kk =
          ((unsigned long long)__float_as_uint(iou) << 32) | (unsigned)(~j);
      key = kk > key ? kk : key;
    }
    unsigned long long o1 = shfl_xor_u64(key, 1); key = o1 > key ? o1 : key;
    unsigned long long o2 = shfl_xor_u64(key, 2); key = o2 > key ? o2 : key;
    if (q == 0 && idx >= 0)
      out[2 * TOTALK + slot] = (int)(~(unsigned)key) & 0xFF;
  }
  __syncthreads();

  // ---- Phase F: cleanup for the next call ----
  for (int t = tid; t < 2 * NBINS; t += 1024) (&g_hist[0][0])[t] = 0;
  if (tid == 0) { g_nbord = 0; g_cntp = 0; g_cntn = 0; }
}

// ---------------------------------------------------------------------------
extern "C" void kernel_launch(void* const* d_in, const int* in_sizes, int n_in,
                              void* d_out, int out_size, void* d_ws, size_t ws_size,
                              hipStream_t stream) {
  (void)in_sizes; (void)n_in; (void)out_size; (void)d_ws; (void)ws_size;
  const float4* anchors = (const float4*)d_in[0];
  const float4* gt      = (const float4*)d_in[1];
  const int*    ph      = (const int*)d_in[2];
  const int*    pw      = (const int*)d_in[3];
  int*          out     = (int*)d_out;

  k_main<<<N_ANCH / 512, 256, 0, stream>>>(anchors, gt, ph, pw);
  k_tail<<<1, 1024, 0, stream>>>(anchors, gt, out);
}

// Round 8
// 124.021 us; speedup vs baseline: 1.7583x; 1.0198x over previous
//
#include <hip/hip_runtime.h>

// Forbid FMA contraction: the reference evaluates each f32 op separately; a
// fused (A+B) - ih*iw would change rounding and can flip labels at 0.3/0.7.
#pragma clang fp contract(off)

#define N_ANCH   262144
#define N_GT     256
#define MAX_POSK 128
#define TOTALK   256
#define NBINS    2048
#define CAP      2048      // filtered candidate LDS cap (actual ~300)
#define BORDCAP  2048
#define CAP_P    32768     // raw positive buffer
#define CAP_N    4096      // raw negative buffer (bin >= T_N)
#define T_N      2032      // top-16-bins prefilter for negatives

// ---------------------------------------------------------------------------
// Threefry-2x32 (exact JAX PRNG). 20 rounds — VERIFIED bit-exact (R2-R7).
// ---------------------------------------------------------------------------
struct TF2 { unsigned a, b; };

__host__ __device__ constexpr unsigned rotl32(unsigned v, int d) {
  return (v << d) | (v >> (32 - d));
}

__host__ __device__ constexpr TF2 tf2x32(unsigned k0, unsigned k1,
                                         unsigned x0, unsigned x1) {
  unsigned ks2 = k0 ^ k1 ^ 0x1BD11BDAu;
  x0 += k0; x1 += k1;
  x0 += x1; x1 = rotl32(x1, 13); x1 ^= x0;
  x0 += x1; x1 = rotl32(x1, 15); x1 ^= x0;
  x0 += x1; x1 = rotl32(x1, 26); x1 ^= x0;
  x0 += x1; x1 = rotl32(x1,  6); x1 ^= x0;
  x0 += k1; x1 += ks2 + 1u;
  x0 += x1; x1 = rotl32(x1, 17); x1 ^= x0;
  x0 += x1; x1 = rotl32(x1, 29); x1 ^= x0;
  x0 += x1; x1 = rotl32(x1, 16); x1 ^= x0;
  x0 += x1; x1 = rotl32(x1, 24); x1 ^= x0;
  x0 += ks2; x1 += k0 + 2u;
  x0 += x1; x1 = rotl32(x1, 13); x1 ^= x0;
  x0 += x1; x1 = rotl32(x1, 15); x1 ^= x0;
  x0 += x1; x1 = rotl32(x1, 26); x1 ^= x0;
  x0 += x1; x1 = rotl32(x1,  6); x1 ^= x0;
  x0 += k0; x1 += k1 + 3u;
  x0 += x1; x1 = rotl32(x1, 17); x1 ^= x0;
  x0 += x1; x1 = rotl32(x1, 29); x1 ^= x0;
  x0 += x1; x1 = rotl32(x1, 16); x1 ^= x0;
  x0 += x1; x1 = rotl32(x1, 24); x1 ^= x0;
  x0 += k1; x1 += ks2 + 4u;
  x0 += x1; x1 = rotl32(x1, 13); x1 ^= x0;
  x0 += x1; x1 = rotl32(x1, 15); x1 ^= x0;
  x0 += x1; x1 = rotl32(x1, 26); x1 ^= x0;
  x0 += x1; x1 = rotl32(x1,  6); x1 ^= x0;
  x0 += ks2; x1 += k0 + 5u;
  return TF2{x0, x1};
}

// jax.random.key(42); partitionable threefry (verified):
//   split: child i = both words of E(key,(0,i));  bits[i] = E(key,(0,i)).a ^ .b
constexpr unsigned KP0 = tf2x32(0u, 42u, 0u, 0u).a;
constexpr unsigned KP1 = tf2x32(0u, 42u, 0u, 0u).b;
constexpr unsigned KN0 = tf2x32(0u, 42u, 0u, 1u).a;
constexpr unsigned KN1 = tf2x32(0u, 42u, 0u, 1u).b;

__device__ inline unsigned score_bits(unsigned k0, unsigned k1, unsigned i) {
  TF2 r = tf2x32(k0, k1, 0u, i);
  return r.a ^ r.b;
}

// Exact threshold constants (verified R3-R7):
// round32(q) > 0.7f  <=> q >= MPOSD ;  round32(q) >= 0.3f <=> q >= MNEGD
constexpr double MPOSD = (double)0.7f + 0x1p-25;
constexpr double MNEGD = (double)0.3f - 0x1p-26;
// inter >= m*(A+B-inter) <=> inter >= [m/(1+m)]*(A+B)
constexpr float CPF = (float)(MPOSD / (1.0 + MPOSD));
constexpr float CNF = (float)(MNEGD / (1.0 + MNEGD));

// ---------------------------------------------------------------------------
// Device-global scratch. Histograms/counters are zero at entry to k_main on
// EVERY call: zero-init at module load, re-zeroed by k_tail's cleanup phase
// each launch (harness only poisons d_out/d_ws; graph replays are complete).
// ---------------------------------------------------------------------------
__device__ unsigned g_packed[N_ANCH];   // (sbits & ~511) | (label+1)
__device__ int      g_hist[2][NBINS];
__device__ int      g_nbord;
__device__ int      g_bord[BORDCAP];
__device__ int      g_cntp, g_cntn;
__device__ int      g_cand_p[CAP_P];    // anchor idx, all positives
__device__ int      g_cand_n[CAP_N];    // anchor idx, negatives with bin >= T_N

// ---------------------------------------------------------------------------
__device__ inline void finish_anchor(int i, float4 a, float mp, float mn,
                                     float Hf, float Wf) {
  const float A = (a.z - a.x) * (a.w - a.y);
  const float mrp = mp - CPF * A;     // sign == sign of best q vs MPOSD (+/- band)
  const float mrn = mn - CNF * A;
  const bool inside = (a.x >= 0.0f) && (a.y >= 0.0f) && (a.z <= Hf) && (a.w <= Wf);
  // rounding-error bound ~6*2^-24*(A+B); band = 12*2^-24*(A+65536) >= 2x slack
  const float band = 0x1.8p-21f * (A + 65536.0f);
  const bool pos = mrp > band;
  const bool nny = mrn > band;
  int lab = pos ? 1 : (nny ? -1 : 0);
  if (!inside) lab = -1;

  unsigned sb = 0u;
  if (lab >= 0) {
    sb = score_bits(lab == 1 ? KP0 : KN0, lab == 1 ? KP1 : KN1, (unsigned)i);
    atomicAdd(&g_hist[lab == 1 ? 0 : 1][sb >> 21], 1);
    if (lab == 1) {
      int q = atomicAdd(&g_cntp, 1);
      if (q < CAP_P) g_cand_p[q] = i;
    } else if ((sb >> 21) >= T_N) {
      int q = atomicAdd(&g_cntn, 1);
      if (q < CAP_N) g_cand_n[q] = i;
    }
  }
  g_packed[i] = (sb & ~511u) | (unsigned)(lab + 1);

  if (inside && (fabsf(mrp) <= band || fabsf(mrn) <= band)) {
    int b = atomicAdd(&g_nbord, 1);
    if (b < BORDCAP) g_bord[b] = i;
  }
}

// 1 anchor/thread, 1024 blocks (4 blocks/CU -> 16 waves/CU: R2-proven TLP).
// Per-j math byte-identical to R4-R7 verified version; j processed in pairs
// with independent accumulator pairs (exact fmax merge) for ILP.
__global__ __launch_bounds__(256) void k_main(const float4* __restrict__ anchors,
                                              const float4* __restrict__ gt,
                                              const int* __restrict__ ph,
                                              const int* __restrict__ pw) {
  __shared__ float4 s_gt[N_GT];
  __shared__ float2 s_tpn[N_GT];   // {CPF*B_j, CNF*B_j}
  const int tid = threadIdx.x;
  {
    float4 g = gt[tid];
    s_gt[tid] = g;
    float B = (g.z - g.x) * (g.w - g.y);
    s_tpn[tid] = make_float2(CPF * B, CNF * B);
  }
  __syncthreads();

  const int i = blockIdx.x * 256 + tid;
  const float4 a = anchors[i];
  const float Hf = (float)(*ph);
  const float Wf = (float)(*pw);

  float mpA = -1e30f, mnA = -1e30f, mpB = -1e30f, mnB = -1e30f;
  #pragma unroll 8
  for (int j = 0; j < N_GT; j += 2) {
    {
      const float4 b = s_gt[j];
      const float2 t = s_tpn[j];
      float ih = fmaxf(fminf(a.z, b.z) - fmaxf(a.x, b.x), 0.0f);
      float iw = fmaxf(fminf(a.w, b.w) - fmaxf(a.y, b.y), 0.0f);
      float in0 = ih * iw;
      mpA = fmaxf(mpA, in0 - t.x);
      mnA = fmaxf(mnA, in0 - t.y);
    }
    {
      const float4 b = s_gt[j + 1];
      const float2 t = s_tpn[j + 1];
      float ih = fmaxf(fminf(a.z, b.z) - fmaxf(a.x, b.x), 0.0f);
      float iw = fmaxf(fminf(a.w, b.w) - fmaxf(a.y, b.y), 0.0f);
      float in1 = ih * iw;
      mpB = fmaxf(mpB, in1 - t.x);
      mnB = fmaxf(mnB, in1 - t.y);
    }
  }
  // fmax merge is exact (no rounding) -> identical classification to serial
  finish_anchor(i, a, fmaxf(mpA, mpB), fmaxf(mnA, mnB), Hf, Wf);
}

__device__ inline unsigned long long shfl_xor_u64(unsigned long long v, int m) {
  unsigned lo = (unsigned)v, hi = (unsigned)(v >> 32);
  lo = __shfl_xor(lo, m, 64);
  hi = __shfl_xor(hi, m, 64);
  return ((unsigned long long)hi << 32) | lo;
}

// Fused tail: hist->LDS -> border-resolve -> parallel totals/cuts ->
// compact-from-buffers -> rank-write -> argmax -> cleanup. (R7-verified.)
__global__ __launch_bounds__(1024) void k_tail(const float4* __restrict__ anchors,
                                               const float4* __restrict__ gt,
                                               int* __restrict__ out) {
  __shared__ unsigned long long s_keys[2][CAP];   // 32 KB: (score23<<32)|~idx
  __shared__ int    s_hist[2][NBINS];             // 16 KB: LDS copy of g_hist
  __shared__ float4 s_gt[N_GT];                   //  4 KB
  __shared__ int    s_cs[2][128];                 // chunk sums (16 bins each)
  __shared__ int    s_sx[2][128];                 // exclusive suffix of chunks
  __shared__ int    s_sel[TOTALK];
  __shared__ int    s_cut[2], s_cnt[2], s_cur[2], s_full;
  const int tid  = threadIdx.x;
  const int wid  = tid >> 6, lane = tid & 63;

  // ---- Phase 0: stage gt + hist into LDS (coalesced) ----
  for (int t = tid; t < N_GT; t += 1024) s_gt[t] = gt[t];
  for (int t = tid; t < 2 * NBINS; t += 1024)
    (&s_hist[0][0])[t] = (&g_hist[0][0])[t];
  if (tid < 2) s_cnt[tid] = 0;
  __syncthreads();

  // ---- Phase A: border resolve (one anchor per wave, exact f64 compares) ----
  int nb = g_nbord; if (nb > BORDCAP) nb = BORDCAP;
  for (int b = wid; b < nb; b += 16) {
    const int i = g_bord[b];
    const float4 a = anchors[i];
    const float A = (a.z - a.x) * (a.w - a.y);
    bool p = false, nn = false;
    #pragma unroll
    for (int k = 0; k < 4; ++k) {
      const int j = lane + 64 * k;
      float4 bb = s_gt[j];
      float ih = fmaxf(fminf(a.z, bb.z) - fmaxf(a.x, bb.x), 0.0f);
      float iw = fmaxf(fminf(a.w, bb.w) - fmaxf(a.y, bb.y), 0.0f);
      float inter = ih * iw;
      float Bar = (bb.z - bb.x) * (bb.w - bb.y);
      float uni = (A + Bar) - inter;          // exact reference f32 rounding
      double id = (double)inter, ud = (double)uni;
      p  |= (id >= MPOSD * ud);               // exact: 25x24-bit products in f64
      nn |= (id >= MNEGD * ud);
    }
    unsigned long long bp = __ballot(p);
    unsigned long long bn = __ballot(nn);
    if (lane == 0) {
      int newlab = bp ? 1 : (bn ? -1 : 0);
      unsigned old = g_packed[i];
      int oldlab = (int)(old & 3u) - 1;
      if (newlab != oldlab) {
        if (oldlab >= 0) atomicAdd(&s_hist[oldlab == 1 ? 0 : 1][old >> 21], -1);
        unsigned sb = 0u;
        if (newlab >= 0) {
          sb = score_bits(newlab == 1 ? KP0 : KN0, newlab == 1 ? KP1 : KN1, (unsigned)i);
          atomicAdd(&s_hist[newlab == 1 ? 0 : 1][sb >> 21], 1);
          if (newlab == 1) {                   // same append rules as k_main
            int q = atomicAdd(&g_cntp, 1);
            if (q < CAP_P) g_cand_p[q] = i;
          } else if ((sb >> 21) >= T_N) {
            int q = atomicAdd(&g_cntn, 1);
            if (q < CAP_N) g_cand_n[q] = i;
          }
        }
        g_packed[i] = (sb & ~511u) | (unsigned)(newlab + 1);
      }
    }
  }
  __syncthreads();

  // ---- Phase B: parallel totals + cutoff bins (all from LDS) ----
  if (tid < 256) {
    const int cls = tid >> 7, c = tid & 127;
    int s = 0;
    #pragma unroll
    for (int b = c * 16; b < c * 16 + 16; ++b) s += s_hist[cls][b];
    s_cs[cls][c] = s;
  }
  __syncthreads();
  if (tid < 256) {
    const int cls = tid >> 7, c = tid & 127;
    int s = 0;
    for (int c2 = c + 1; c2 < 128; ++c2) s += s_cs[cls][c2];
    s_sx[cls][c] = s;
  }
  __syncthreads();
  if (tid == 0) {
    int total_p = s_sx[0][0] + s_cs[0][0];
    int total_n = s_sx[1][0] + s_cs[1][0];
    int cur_pos = total_p < MAX_POSK ? total_p : MAX_POSK;
    int rem = TOTALK - cur_pos;
    int cur_neg = total_n < rem ? total_n : rem;
    s_cur[0] = cur_pos;
    s_cur[1] = cur_neg;
    s_cut[0] = NBINS;          // default for K<=0; overwritten by owner chunk
    s_cut[1] = NBINS;
  }
  __syncthreads();
  // cut = largest b with suffix(b) >= K; unique owner chunk writes it.
  if (tid < 256) {
    const int cls = tid >> 7, c = tid & 127;
    const int K = s_cur[cls];
    if (K > 0) {
      const int sx = s_sx[cls][c];
      if (sx < K && sx + s_cs[cls][c] >= K) {
        int suffix = sx;
        int cut = c * 16;
        for (int b = c * 16 + 15; b >= c * 16; --b) {
          suffix += s_hist[cls][b];
          if (suffix >= K) { cut = b; break; }
        }
        s_cut[cls] = cut;
      }
    }
  }
  __syncthreads();
  if (tid == 0) {
    // Exact safety: buffer path valid iff no overflow and cut_n >= T_N
    // (cut_n >= T_N holds whenever suffix(T_N) >= cur_neg; ~24 sigma margin).
    s_full = (g_cntp > CAP_P) || (g_cntn > CAP_N) ||
             (s_cur[1] > 0 && s_cut[1] < T_N);
  }
  __syncthreads();

  // ---- Phase C: compact candidates into LDS (from small buffers) ----
  const int cut0 = s_cut[0], cut1 = s_cut[1];
  if (!s_full) {
    int Cp = g_cntp;                          // <= CAP_P (checked)
    for (int t = tid; t < Cp; t += 1024) {
      const int i = g_cand_p[t];
      const unsigned p = g_packed[i];         // re-read: honors border flips
      if ((p & 3u) == 2u && (int)(p >> 21) >= cut0) {
        int q = atomicAdd(&s_cnt[0], 1);
        if (q < CAP)
          s_keys[0][q] = ((unsigned long long)(p >> 9) << 32) | (unsigned)(~i);
      }
    }
    int Cn = g_cntn;
    for (int t = tid; t < Cn; t += 1024) {
      const int i = g_cand_n[t];
      const unsigned p = g_packed[i];
      if ((p & 3u) == 1u && (int)(p >> 21) >= cut1) {
        int q = atomicAdd(&s_cnt[1], 1);
        if (q < CAP)
          s_keys[1][q] = ((unsigned long long)(p >> 9) << 32) | (unsigned)(~i);
      }
    }
  } else {
    // Never-triggered exact fallback: full scan (slow, single block).
    for (int i = tid; i < N_ANCH; i += 1024) {
      const unsigned p = g_packed[i];
      const int lab0 = (int)(p & 3u);
      if (lab0 == 0) continue;
      const int s = (lab0 == 2) ? 0 : 1;
      if ((int)(p >> 21) >= (s == 0 ? cut0 : cut1)) {
        int q = atomicAdd(&s_cnt[s], 1);
        if (q < CAP)
          s_keys[s][q] = ((unsigned long long)(p >> 9) << 32) | (unsigned)(~i);
      }
    }
  }
  for (int t = tid; t < TOTALK; t += 1024) s_sel[t] = -1;
  for (int t = tid; t < 3 * TOTALK; t += 1024) out[t] = -1;
  __syncthreads();

  // ---- Phase D: rank-write (rank = #keys greater; unique by idx tiebreak) ----
  const int cur_pos = s_cur[0], cur_neg = s_cur[1];
  if (tid == 0) out[3 * TOTALK] = cur_pos;
  int Cp = s_cnt[0]; if (Cp > CAP) Cp = CAP;
  int Cn = s_cnt[1]; if (Cn > CAP) Cn = CAP;
  for (int t = tid; t < Cp; t += 1024) {
    unsigned long long me = s_keys[0][t];
    int r = 0;
    for (int u = 0; u < Cp; ++u) r += (s_keys[0][u] > me);
    if (r < cur_pos) {
      int idx = (int)(~(unsigned)me);
      s_sel[r] = idx;
      out[r] = idx;
      out[TOTALK + r] = 1;
    }
  }
  for (int t = tid; t < Cn; t += 1024) {
    unsigned long long me = s_keys[1][t];
    int r = 0;
    for (int u = 0; u < Cn; ++u) r += (s_keys[1][u] > me);
    if (r < cur_neg) {
      int idx = (int)(~(unsigned)me);
      s_sel[cur_pos + r] = idx;
      out[cur_pos + r] = idx;
      out[TOTALK + cur_pos + r] = 0;
    }
  }
  __syncthreads();

  // ---- Phase E: argmax for selected slots (IEEE f32 div, first-max) ----
  {
    const int slot = tid >> 2;                // 0..255
    const int q    = tid & 3;                 // GT quarter
    const int idx  = s_sel[slot];
    const int safe = idx < 0 ? 0 : idx;
    const float4 a = anchors[safe];
    const float A = (a.z - a.x) * (a.w - a.y);
    unsigned long long key = 0ULL;
    for (int k = 0; k < 64; ++k) {
      const int j = q * 64 + k;
      const float4 b = s_gt[j];
      const float B = (b.z - b.x) * (b.w - b.y);
      float ih = fmaxf(fminf(a.z, b.z) - fmaxf(a.x, b.x), 0.0f);
      float iw = fmaxf(fminf(a.w, b.w) - fmaxf(a.y, b.y), 0.0f);
      float inter = ih * iw;
      float uni = (A + B) - inter;
      float iou = inter / fmaxf(uni, 1e-8f);  // IEEE-exact, matches reference
      unsigned long long kk =
          ((unsigned long long)__float_as_uint(iou) << 32) | (unsigned)(~j);
      key = kk > key ? kk : key;
    }
    unsigned long long o1 = shfl_xor_u64(key, 1); key = o1 > key ? o1 : key;
    unsigned long long o2 = shfl_xor_u64(key, 2); key = o2 > key ? o2 : key;
    if (q == 0 && idx >= 0)
      out[2 * TOTALK + slot] = (int)(~(unsigned)key) & 0xFF;
  }
  __syncthreads();

  // ---- Phase F: cleanup for the next call ----
  for (int t = tid; t < 2 * NBINS; t += 1024) (&g_hist[0][0])[t] = 0;
  if (tid == 0) { g_nbord = 0; g_cntp = 0; g_cntn = 0; }
}

// ---------------------------------------------------------------------------
extern "C" void kernel_launch(void* const* d_in, const int* in_sizes, int n_in,
                              void* d_out, int out_size, void* d_ws, size_t ws_size,
                              hipStream_t stream) {
  (void)in_sizes; (void)n_in; (void)out_size; (void)d_ws; (void)ws_size;
  const float4* anchors = (const float4*)d_in[0];
  const float4* gt      = (const float4*)d_in[1];
  const int*    ph      = (const int*)d_in[2];
  const int*    pw      = (const int*)d_in[3];
  int*          out     = (int*)d_out;

  k_main<<<N_ANCH / 256, 256, 0, stream>>>(anchors, gt, ph, pw);
  k_tail<<<1, 1024, 0, stream>>>(anchors, gt, out);
}

// Round 9
// 117.896 us; speedup vs baseline: 1.8496x; 1.0520x over previous
//
#include <hip/hip_runtime.h>

// Forbid FMA contraction: the reference evaluates each f32 op separately; a
// fused (A+B) - ih*iw would change rounding and can flip labels at 0.3/0.7.
#pragma clang fp contract(off)

#define N_ANCH   262144
#define N_GT     256
#define MAX_POSK 128
#define TOTALK   256
#define NBINS    2048
#define CAP      2048      // filtered candidate LDS cap (actual ~300)
#define BORDCAP  2048
#define CAP_P    32768     // raw positive buffer
#define CAP_N    4096      // raw negative buffer (bin >= T_N)
#define T_N      2032      // top-16-bins prefilter for negatives

// ---------------------------------------------------------------------------
// Threefry-2x32 (exact JAX PRNG). 20 rounds — VERIFIED bit-exact (R2-R8).
// ---------------------------------------------------------------------------
struct TF2 { unsigned a, b; };

__host__ __device__ constexpr unsigned rotl32(unsigned v, int d) {
  return (v << d) | (v >> (32 - d));
}

__host__ __device__ constexpr TF2 tf2x32(unsigned k0, unsigned k1,
                                         unsigned x0, unsigned x1) {
  unsigned ks2 = k0 ^ k1 ^ 0x1BD11BDAu;
  x0 += k0; x1 += k1;
  x0 += x1; x1 = rotl32(x1, 13); x1 ^= x0;
  x0 += x1; x1 = rotl32(x1, 15); x1 ^= x0;
  x0 += x1; x1 = rotl32(x1, 26); x1 ^= x0;
  x0 += x1; x1 = rotl32(x1,  6); x1 ^= x0;
  x0 += k1; x1 += ks2 + 1u;
  x0 += x1; x1 = rotl32(x1, 17); x1 ^= x0;
  x0 += x1; x1 = rotl32(x1, 29); x1 ^= x0;
  x0 += x1; x1 = rotl32(x1, 16); x1 ^= x0;
  x0 += x1; x1 = rotl32(x1, 24); x1 ^= x0;
  x0 += ks2; x1 += k0 + 2u;
  x0 += x1; x1 = rotl32(x1, 13); x1 ^= x0;
  x0 += x1; x1 = rotl32(x1, 15); x1 ^= x0;
  x0 += x1; x1 = rotl32(x1, 26); x1 ^= x0;
  x0 += x1; x1 = rotl32(x1,  6); x1 ^= x0;
  x0 += k0; x1 += k1 + 3u;
  x0 += x1; x1 = rotl32(x1, 17); x1 ^= x0;
  x0 += x1; x1 = rotl32(x1, 29); x1 ^= x0;
  x0 += x1; x1 = rotl32(x1, 16); x1 ^= x0;
  x0 += x1; x1 = rotl32(x1, 24); x1 ^= x0;
  x0 += k1; x1 += ks2 + 4u;
  x0 += x1; x1 = rotl32(x1, 13); x1 ^= x0;
  x0 += x1; x1 = rotl32(x1, 15); x1 ^= x0;
  x0 += x1; x1 = rotl32(x1, 26); x1 ^= x0;
  x0 += x1; x1 = rotl32(x1,  6); x1 ^= x0;
  x0 += ks2; x1 += k0 + 5u;
  return TF2{x0, x1};
}

// jax.random.key(42); partitionable threefry (verified):
//   split: child i = both words of E(key,(0,i));  bits[i] = E(key,(0,i)).a ^ .b
constexpr unsigned KP0 = tf2x32(0u, 42u, 0u, 0u).a;
constexpr unsigned KP1 = tf2x32(0u, 42u, 0u, 0u).b;
constexpr unsigned KN0 = tf2x32(0u, 42u, 0u, 1u).a;
constexpr unsigned KN1 = tf2x32(0u, 42u, 0u, 1u).b;

__device__ inline unsigned score_bits(unsigned k0, unsigned k1, unsigned i) {
  TF2 r = tf2x32(k0, k1, 0u, i);
  return r.a ^ r.b;
}

// Exact threshold constants (verified R3-R8):
// round32(q) > 0.7f  <=> q >= MPOSD ;  round32(q) >= 0.3f <=> q >= MNEGD
constexpr double MPOSD = (double)0.7f + 0x1p-25;
constexpr double MNEGD = (double)0.3f - 0x1p-26;
// inter >= m*(A+B-inter) <=> inter >= [m/(1+m)]*(A+B)
constexpr float CPF = (float)(MPOSD / (1.0 + MPOSD));
constexpr float CNF = (float)(MNEGD / (1.0 + MNEGD));

// ---------------------------------------------------------------------------
// Device-global scratch. Histograms/counters are zero at entry to k_main on
// EVERY call: zero-init at module load, re-zeroed by k_tail's cleanup phase
// each launch (harness only poisons d_out/d_ws; graph replays are complete).
// ---------------------------------------------------------------------------
__device__ unsigned g_packed[N_ANCH];   // (sbits & ~511) | (label+1)
__device__ int      g_hist[2][NBINS];
__device__ int      g_nbord;
__device__ int      g_bord[BORDCAP];
__device__ int      g_cntp, g_cntn;
__device__ int      g_cand_p[CAP_P];    // anchor idx, all positives
__device__ int      g_cand_n[CAP_N];    // anchor idx, negatives with bin >= T_N

// ---------------------------------------------------------------------------
__device__ inline void finish_anchor(int i, float4 a, float mp, float mn,
                                     float Hf, float Wf) {
  const float A = (a.z - a.x) * (a.w - a.y);
  const float mrp = mp - CPF * A;     // sign == sign of best q vs MPOSD (+/- band)
  const float mrn = mn - CNF * A;
  const bool inside = (a.x >= 0.0f) && (a.y >= 0.0f) && (a.z <= Hf) && (a.w <= Wf);
  // rounding-error bound ~6*2^-24*(A+B); band = 12*2^-24*(A+65536) >= 2x slack
  const float band = 0x1.8p-21f * (A + 65536.0f);
  const bool pos = mrp > band;
  const bool nny = mrn > band;
  int lab = pos ? 1 : (nny ? -1 : 0);
  if (!inside) lab = -1;

  unsigned sb = 0u;
  if (lab >= 0) {
    sb = score_bits(lab == 1 ? KP0 : KN0, lab == 1 ? KP1 : KN1, (unsigned)i);
    atomicAdd(&g_hist[lab == 1 ? 0 : 1][sb >> 21], 1);
    if (lab == 1) {
      int q = atomicAdd(&g_cntp, 1);
      if (q < CAP_P) g_cand_p[q] = i;
    } else if ((sb >> 21) >= T_N) {
      int q = atomicAdd(&g_cntn, 1);
      if (q < CAP_N) g_cand_n[q] = i;
    }
  }
  g_packed[i] = (sb & ~511u) | (unsigned)(lab + 1);

  if (inside && (fabsf(mrp) <= band || fabsf(mrn) <= band)) {
    int b = atomicAdd(&g_nbord, 1);
    if (b < BORDCAP) g_bord[b] = i;
  }
}

// 1 anchor/thread, 1024 blocks. GT boxes are wave-uniform -> read straight
// from global with a uniform index so the compiler emits s_load into SGPRs
// (zero VALU slots, no LDS for b). Only {tp,tn} pairs live in LDS (one
// ds_read_b128 per 2 j). Per-j math byte-identical to R4-R8 verified version.
__global__ __launch_bounds__(256) void k_main(const float4* __restrict__ anchors,
                                              const float4* __restrict__ gt,
                                              const int* __restrict__ ph,
                                              const int* __restrict__ pw) {
  __shared__ float4 s_tpn2[N_GT / 2];   // {tp_j, tn_j, tp_j+1, tn_j+1}
  const int tid = threadIdx.x;
  if (tid < N_GT / 2) {
    float4 g0 = gt[2 * tid];
    float4 g1 = gt[2 * tid + 1];
    float B0 = (g0.z - g0.x) * (g0.w - g0.y);   // same exprs as R8 setup
    float B1 = (g1.z - g1.x) * (g1.w - g1.y);
    s_tpn2[tid] = make_float4(CPF * B0, CNF * B0, CPF * B1, CNF * B1);
  }
  __syncthreads();

  const int i = blockIdx.x * 256 + tid;
  const float4 a = anchors[i];
  const float Hf = (float)(*ph);
  const float Wf = (float)(*pw);

  float mpA = -1e30f, mnA = -1e30f, mpB = -1e30f, mnB = -1e30f;
  #pragma unroll 4
  for (int jp = 0; jp < N_GT / 2; ++jp) {
    const float4 b0 = gt[2 * jp];       // uniform -> s_load (SGPR)
    const float4 b1 = gt[2 * jp + 1];
    const float4 t  = s_tpn2[jp];       // one ds_read_b128 per pair
    {
      float ih = fmaxf(fminf(a.z, b0.z) - fmaxf(a.x, b0.x), 0.0f);
      float iw = fmaxf(fminf(a.w, b0.w) - fmaxf(a.y, b0.y), 0.0f);
      float in0 = ih * iw;
      mpA = fmaxf(mpA, in0 - t.x);
      mnA = fmaxf(mnA, in0 - t.y);
    }
    {
      float ih = fmaxf(fminf(a.z, b1.z) - fmaxf(a.x, b1.x), 0.0f);
      float iw = fmaxf(fminf(a.w, b1.w) - fmaxf(a.y, b1.y), 0.0f);
      float in1 = ih * iw;
      mpB = fmaxf(mpB, in1 - t.z);
      mnB = fmaxf(mnB, in1 - t.w);
    }
  }
  // fmax merge is exact (no rounding) -> identical classification to serial
  finish_anchor(i, a, fmaxf(mpA, mpB), fmaxf(mnA, mnB), Hf, Wf);
}

__device__ inline unsigned long long shfl_xor_u64(unsigned long long v, int m) {
  unsigned lo = (unsigned)v, hi = (unsigned)(v >> 32);
  lo = __shfl_xor(lo, m, 64);
  hi = __shfl_xor(hi, m, 64);
  return ((unsigned long long)hi << 32) | lo;
}

// Fused tail: border-resolve (patches GLOBAL hist) -> register-direct
// totals/cuts -> compact-from-buffers -> rank-write -> argmax -> cleanup.
__global__ __launch_bounds__(1024) void k_tail(const float4* __restrict__ anchors,
                                               const float4* __restrict__ gt,
                                               int* __restrict__ out) {
  __shared__ unsigned long long s_keys[2][CAP];   // 32 KB: (score23<<32)|~idx
  __shared__ float4 s_gt[N_GT];                   //  4 KB
  __shared__ int    s_cs[2][128];                 // chunk sums (16 bins each)
  __shared__ int    s_sx[2][128];                 // exclusive suffix of chunks
  __shared__ int    s_sel[TOTALK];
  __shared__ int    s_cut[2], s_cnt[2], s_cur[2], s_full;
  const int tid  = threadIdx.x;
  const int wid  = tid >> 6, lane = tid & 63;

  // ---- Phase 0: stage gt into LDS (coalesced) ----
  for (int t = tid; t < N_GT; t += 1024) s_gt[t] = gt[t];
  if (tid < 2) s_cnt[tid] = 0;
  __syncthreads();

  // ---- Phase A: border resolve (one anchor per wave, exact f64 compares),
  //      patches GLOBAL hist/buffers (nb is O(1), cost negligible) ----
  int nb = g_nbord; if (nb > BORDCAP) nb = BORDCAP;
  for (int b = wid; b < nb; b += 16) {
    const int i = g_bord[b];
    const float4 a = anchors[i];
    const float A = (a.z - a.x) * (a.w - a.y);
    bool p = false, nn = false;
    #pragma unroll
    for (int k = 0; k < 4; ++k) {
      const int j = lane + 64 * k;
      float4 bb = s_gt[j];
      float ih = fmaxf(fminf(a.z, bb.z) - fmaxf(a.x, bb.x), 0.0f);
      float iw = fmaxf(fminf(a.w, bb.w) - fmaxf(a.y, bb.y), 0.0f);
      float inter = ih * iw;
      float Bar = (bb.z - bb.x) * (bb.w - bb.y);
      float uni = (A + Bar) - inter;          // exact reference f32 rounding
      double id = (double)inter, ud = (double)uni;
      p  |= (id >= MPOSD * ud);               // exact: 25x24-bit products in f64
      nn |= (id >= MNEGD * ud);
    }
    unsigned long long bp = __ballot(p);
    unsigned long long bn = __ballot(nn);
    if (lane == 0) {
      int newlab = bp ? 1 : (bn ? -1 : 0);
      unsigned old = g_packed[i];
      int oldlab = (int)(old & 3u) - 1;
      if (newlab != oldlab) {
        if (oldlab >= 0) atomicAdd(&g_hist[oldlab == 1 ? 0 : 1][old >> 21], -1);
        unsigned sb = 0u;
        if (newlab >= 0) {
          sb = score_bits(newlab == 1 ? KP0 : KN0, newlab == 1 ? KP1 : KN1, (unsigned)i);
          atomicAdd(&g_hist[newlab == 1 ? 0 : 1][sb >> 21], 1);
          if (newlab == 1) {                   // same append rules as k_main
            int q = atomicAdd(&g_cntp, 1);
            if (q < CAP_P) g_cand_p[q] = i;
          } else if ((sb >> 21) >= T_N) {
            int q = atomicAdd(&g_cntn, 1);
            if (q < CAP_N) g_cand_n[q] = i;
          }
        }
        g_packed[i] = (sb & ~511u) | (unsigned)(newlab + 1);
      }
    }
  }
  __syncthreads();

  // ---- Phase B: totals + cutoff bins (hist read once into registers) ----
  int h[16];
  if (tid < 256) {
    const int cls = tid >> 7, c = tid & 127;
    int s = 0;
    #pragma unroll
    for (int k = 0; k < 16; ++k) { h[k] = g_hist[cls][c * 16 + k]; s += h[k]; }
    s_cs[cls][c] = s;
  }
  __syncthreads();
  if (tid < 256) {
    const int cls = tid >> 7, c = tid & 127;
    int s = 0;
    for (int c2 = c + 1; c2 < 128; ++c2) s += s_cs[cls][c2];
    s_sx[cls][c] = s;
  }
  __syncthreads();
  if (tid == 0) {
    int total_p = s_sx[0][0] + s_cs[0][0];
    int total_n = s_sx[1][0] + s_cs[1][0];
    int cur_pos = total_p < MAX_POSK ? total_p : MAX_POSK;
    int rem = TOTALK - cur_pos;
    int cur_neg = total_n < rem ? total_n : rem;
    s_cur[0] = cur_pos;
    s_cur[1] = cur_neg;
    s_cut[0] = NBINS;          // default for K<=0; overwritten by owner chunk
    s_cut[1] = NBINS;
  }
  __syncthreads();
  // cut = largest b with suffix(b) >= K; unique owner chunk writes it,
  // walking its 16 bins from the registers loaded in B1. Identical semantics
  // to the R3-R8 verified find_cut.
  if (tid < 256) {
    const int cls = tid >> 7, c = tid & 127;
    const int K = s_cur[cls];
    if (K > 0) {
      const int sx = s_sx[cls][c];
      if (sx < K && sx + s_cs[cls][c] >= K) {
        int suffix = sx;
        int cut = c * 16;
        #pragma unroll
        for (int k = 15; k >= 0; --k) {
          suffix += h[k];
          if (suffix >= K) { cut = c * 16 + k; break; }
        }
        s_cut[cls] = cut;
      }
    }
  }
  __syncthreads();
  if (tid == 0) {
    // Exact safety: buffer path valid iff no overflow and cut_n >= T_N
    // (cut_n >= T_N holds whenever suffix(T_N) >= cur_neg; ~24 sigma margin).
    s_full = (g_cntp > CAP_P) || (g_cntn > CAP_N) ||
             (s_cur[1] > 0 && s_cut[1] < T_N);
  }
  __syncthreads();

  // ---- Phase C: compact candidates into LDS (from small buffers) ----
  const int cut0 = s_cut[0], cut1 = s_cut[1];
  if (!s_full) {
    int Cp = g_cntp;                          // <= CAP_P (checked)
    for (int t = tid; t < Cp; t += 1024) {
      const int i = g_cand_p[t];
      const unsigned p = g_packed[i];         // re-read: honors border flips
      if ((p & 3u) == 2u && (int)(p >> 21) >= cut0) {
        int q = atomicAdd(&s_cnt[0], 1);
        if (q < CAP)
          s_keys[0][q] = ((unsigned long long)(p >> 9) << 32) | (unsigned)(~i);
      }
    }
    int Cn = g_cntn;
    for (int t = tid; t < Cn; t += 1024) {
      const int i = g_cand_n[t];
      const unsigned p = g_packed[i];
      if ((p & 3u) == 1u && (int)(p >> 21) >= cut1) {
        int q = atomicAdd(&s_cnt[1], 1);
        if (q < CAP)
          s_keys[1][q] = ((unsigned long long)(p >> 9) << 32) | (unsigned)(~i);
      }
    }
  } else {
    // Never-triggered exact fallback: full scan (slow, single block).
    for (int i = tid; i < N_ANCH; i += 1024) {
      const unsigned p = g_packed[i];
      const int lab0 = (int)(p & 3u);
      if (lab0 == 0) continue;
      const int s = (lab0 == 2) ? 0 : 1;
      if ((int)(p >> 21) >= (s == 0 ? cut0 : cut1)) {
        int q = atomicAdd(&s_cnt[s], 1);
        if (q < CAP)
          s_keys[s][q] = ((unsigned long long)(p >> 9) << 32) | (unsigned)(~i);
      }
    }
  }
  for (int t = tid; t < TOTALK; t += 1024) s_sel[t] = -1;
  for (int t = tid; t < 3 * TOTALK; t += 1024) out[t] = -1;
  __syncthreads();

  // ---- Phase D: rank-write (rank = #keys greater; unique by idx tiebreak) ----
  const int cur_pos = s_cur[0], cur_neg = s_cur[1];
  if (tid == 0) out[3 * TOTALK] = cur_pos;
  int Cp = s_cnt[0]; if (Cp > CAP) Cp = CAP;
  int Cn = s_cnt[1]; if (Cn > CAP) Cn = CAP;
  for (int t = tid; t < Cp; t += 1024) {
    unsigned long long me = s_keys[0][t];
    int r = 0;
    for (int u = 0; u < Cp; ++u) r += (s_keys[0][u] > me);
    if (r < cur_pos) {
      int idx = (int)(~(unsigned)me);
      s_sel[r] = idx;
      out[r] = idx;
      out[TOTALK + r] = 1;
    }
  }
  for (int t = tid; t < Cn; t += 1024) {
    unsigned long long me = s_keys[1][t];
    int r = 0;
    for (int u = 0; u < Cn; ++u) r += (s_keys[1][u] > me);
    if (r < cur_neg) {
      int idx = (int)(~(unsigned)me);
      s_sel[cur_pos + r] = idx;
      out[cur_pos + r] = idx;
      out[TOTALK + cur_pos + r] = 0;
    }
  }
  __syncthreads();

  // ---- Phase E: argmax for selected slots (IEEE f32 div, first-max) ----
  {
    const int slot = tid >> 2;                // 0..255
    const int q    = tid & 3;                 // GT quarter
    const int idx  = s_sel[slot];
    const int safe = idx < 0 ? 0 : idx;
    const float4 a = anchors[safe];
    const float A = (a.z - a.x) * (a.w - a.y);
    unsigned long long key = 0ULL;
    for (int k = 0; k < 64; ++k) {
      const int j = q * 64 + k;
      const float4 b = s_gt[j];
      const float B = (b.z - b.x) * (b.w - b.y);
      float ih = fmaxf(fminf(a.z, b.z) - fmaxf(a.x, b.x), 0.0f);
      float iw = fmaxf(fminf(a.w, b.w) - fmaxf(a.y, b.y), 0.0f);
      float inter = ih * iw;
      float uni = (A + B) - inter;
      float iou = inter / fmaxf(uni, 1e-8f);  // IEEE-exact, matches reference
      unsigned long long kk =
          ((unsigned long long)__float_as_uint(iou) << 32) | (unsigned)(~j);
      key = kk > key ? kk : key;
    }
    unsigned long long o1 = shfl_xor_u64(key, 1); key = o1 > key ? o1 : key;
    unsigned long long o2 = shfl_xor_u64(key, 2); key = o2 > key ? o2 : key;
    if (q == 0 && idx >= 0)
      out[2 * TOTALK + slot] = (int)(~(unsigned)key) & 0xFF;
  }
  __syncthreads();

  // ---- Phase F: cleanup for the next call ----
  for (int t = tid; t < 2 * NBINS; t += 1024) (&g_hist[0][0])[t] = 0;
  if (tid == 0) { g_nbord = 0; g_cntp = 0; g_cntn = 0; }
}

// ---------------------------------------------------------------------------
extern "C" void kernel_launch(void* const* d_in, const int* in_sizes, int n_in,
                              void* d_out, int out_size, void* d_ws, size_t ws_size,
                              hipStream_t stream) {
  (void)in_sizes; (void)n_in; (void)out_size; (void)d_ws; (void)ws_size;
  const float4* anchors = (const float4*)d_in[0];
  const float4* gt      = (const float4*)d_in[1];
  const int*    ph      = (const int*)d_in[2];
  const int*    pw      = (const int*)d_in[3];
  int*          out     = (int*)d_out;

  k_main<<<N_ANCH / 256, 256, 0, stream>>>(anchors, gt, ph, pw);
  k_tail<<<1, 1024, 0, stream>>>(anchors, gt, out);
}